// Round 9
// baseline (3011.936 us; speedup 1.0000x reference)
//
#include <hip/hip_runtime.h>

#define INPUT 64
#define HID 256
#define BATCH 128
#define TSTEPS 1000
#define KTOT 320            // 256 (h) + 64 (x)

typedef __bf16 bf16_t;
typedef __bf16 bf16x8 __attribute__((ext_vector_type(8)));
typedef float  f32x4  __attribute__((ext_vector_type(4)));

// ---- ws layout (bytes) ----
#define WPACK_OFF   0
#define WPACK_BYTES (1024 * KTOT * 2)            // 655360
#define BIAS_OFF    (WPACK_OFF + WPACK_BYTES)
#define BIAS_BYTES  (1024 * 4)
#define EXCH_OFF    (BIAS_OFF + BIAS_BYTES)      // 16 blocks x 2 parity x 2048 bf16
#define EXCH_BYTES  (16 * 2 * 2048 * 2)          // 131072
#define FLAG_OFF    (EXCH_OFF + EXCH_BYTES)      // 16 flags, 256B apart

__global__ void lstm_prep(
    const float* __restrict__ Wii, const float* __restrict__ Wif,
    const float* __restrict__ Wig, const float* __restrict__ Wio,
    const float* __restrict__ Whi, const float* __restrict__ Whf,
    const float* __restrict__ Whg, const float* __restrict__ Who,
    const float* __restrict__ bii, const float* __restrict__ bif,
    const float* __restrict__ big, const float* __restrict__ bio,
    const float* __restrict__ bhi, const float* __restrict__ bhf,
    const float* __restrict__ bhg, const float* __restrict__ bho,
    bf16_t* __restrict__ wpack, float* __restrict__ bias,
    int* __restrict__ flags)
{
    int id = blockIdx.x * 256 + threadIdx.x;
    if (id < 1024 * KTOT) {
        int n = id / KTOT, k = id % KTOT;
        int g = n >> 8, j = n & 255;
        const float* Wh = (g == 0) ? Whi : (g == 1) ? Whf : (g == 2) ? Whg : Who;
        const float* Wi = (g == 0) ? Wii : (g == 1) ? Wif : (g == 2) ? Wig : Wio;
        float v = (k < HID) ? Wh[j * HID + k] : Wi[j * INPUT + (k - HID)];
        wpack[id] = (bf16_t)v;
    }
    if (id < 1024) {
        int g = id >> 8, j = id & 255;
        const float* bi = (g == 0) ? bii : (g == 1) ? bif : (g == 2) ? big : bio;
        const float* bh = (g == 0) ? bhi : (g == 1) ? bhf : (g == 2) ? bhg : bho;
        bias[id] = bi[j] + bh[j];
    }
    if (id < 16)
        __hip_atomic_store(flags + id * 64, 0, __ATOMIC_RELAXED, __HIP_MEMORY_SCOPE_AGENT);
}

__device__ __forceinline__ float sigmoid_f(float v) {
    return 1.0f / (1.0f + __expf(-v));
}
__device__ __forceinline__ float tanh_f(float v) {
    return 1.0f - 2.0f / (__expf(2.0f * v) + 1.0f);
}

// 16 blocks x 256 threads. group = bid&7, half = bid>>3 (pair b, b+8).
// Wave w (0..3) owns cols [w*32, w*32+32) of the half, ALL 4 gates:
// 4 gates x 2 ntiles x 10 kslices = 80 frags = 320 VGPRs, resident at
// waves_per_eu(1,1) (the only proven-residency config: R4/R5).
// R7-proven exchange protocol + in-register epilogue, 2 barriers/step.
__global__ __launch_bounds__(256) __attribute__((amdgpu_waves_per_eu(1, 1)))
void lstm_main(
    const float* __restrict__ x, const bf16_t* __restrict__ wpack,
    const float* __restrict__ bias_g, float* __restrict__ out,
    bf16_t* __restrict__ exch, int* __restrict__ flags)
{
    // [parity][16 rows][328 bf16]: K 0..255 = h (both halves), 256..319 = x.
    __shared__ __align__(16) bf16_t hxx[2][16 * 328];

    const int bid   = blockIdx.x;
    const int group = bid & 7;
    const int half  = bid >> 3;
    const int tid   = threadIdx.x;
    const int w     = tid >> 6;          // wave 0..3
    const int l     = tid & 63;
    const int col   = l & 15;
    const int kb    = l >> 4;            // 0..3
    const int jbase = w * 32;            // wave's col window within the half

    // ---- persistent weights: 4 gates x 2 ntiles x 10 ks = 320 VGPRs ----
    bf16x8 bW[4][2][10];
#pragma unroll
    for (int g = 0; g < 4; ++g)
#pragma unroll
        for (int n = 0; n < 2; ++n) {
            const int jg = half * 128 + jbase + n * 16 + col;
            const bf16_t* wrow = wpack + (size_t)(g * 256 + jg) * KTOT;
#pragma unroll
            for (int ks = 0; ks < 10; ++ks)
                bW[g][n][ks] = *(const bf16x8*)(wrow + ks * 32 + kb * 8);
        }
#pragma unroll
    for (int g = 0; g < 4; ++g)
#pragma unroll
        for (int n = 0; n < 2; ++n)
#pragma unroll
            for (int ks = 0; ks < 10; ++ks)
                asm volatile("" : "+v"(bW[g][n][ks]));

    float bias_r[4][2];
#pragma unroll
    for (int g = 0; g < 4; ++g)
#pragma unroll
        for (int n = 0; n < 2; ++n)
            bias_r[g][n] = bias_g[g * 256 + half * 128 + jbase + n * 16 + col];

    float c_st[2][4] = {{0.f, 0.f, 0.f, 0.f}, {0.f, 0.f, 0.f, 0.f}};

    const int pbid = (1 - half) * 8 + group;
    int*       flag_me = flags + bid * 64;
    const int* flag_pn = flags + pbid * 64;
    const int  pbase   = (1 - half) * 128;     // partner cols in hxx (elements)

    // partner fetch: thread -> (row prow, 8 bf16 at pe0), 16B per thread
    const int prow = tid >> 4;
    const int pe0  = (tid & 15) * 8;

    // x staging: thread -> (row xr, 4 f32 at xi0)
    const int xr  = tid >> 4;
    const int xi0 = (tid & 15) * 4;
    const float* xbase = x + (size_t)(group * 16 + xr) * (TSTEPS * INPUT) + xi0;

    // prologue: x_0 -> hxx[0], x_1 -> regs
    {
        float4 v = *(const float4*)(xbase);
        bf16_t* d = &hxx[0][xr * 328 + 256 + xi0];
        d[0] = (bf16_t)v.x; d[1] = (bf16_t)v.y; d[2] = (bf16_t)v.z; d[3] = (bf16_t)v.w;
    }
    float4 xv = *(const float4*)(xbase + INPUT);
    __syncthreads();

#pragma unroll 1
    for (int t = 0; t < TSTEPS; ++t) {
        const int cur = t & 1;
        const int nxt = cur ^ 1;

        // ---- P1: stage x_{t+1} -> hxx[nxt]; fetch partner h_{t-1} -> hxx[cur]
        if (t + 1 < TSTEPS) {
            bf16_t* d = &hxx[nxt][xr * 328 + 256 + xi0];
            d[0] = (bf16_t)xv.x; d[1] = (bf16_t)xv.y; d[2] = (bf16_t)xv.z; d[3] = (bf16_t)xv.w;
        }
        if (t + 2 < TSTEPS)
            xv = *(const float4*)(xbase + (size_t)(t + 2) * INPUT);
        if (t > 0) {
            if (l == 0) {
                while (__hip_atomic_load(flag_pn, __ATOMIC_RELAXED, __HIP_MEMORY_SCOPE_AGENT) < t) {}
            }
            const bf16_t* src = exch + ((size_t)pbid * 2 + ((t - 1) & 1)) * 2048
                              + prow * 128 + pe0;
            f32x4 v0;
            asm volatile(
                "global_load_dwordx4 %0, %1, off sc0\n\t"
                "s_waitcnt vmcnt(0)"
                : "=&v"(v0) : "v"(src) : "memory");
            *(f32x4*)&hxx[cur][prow * 328 + pbase + pe0] = v0;
        }
        __syncthreads();                                   // B1: hxx[cur] complete

        // ---- P2: 80 MFMAs, weights resident ----
        f32x4 acc[4][2];
#pragma unroll
        for (int g = 0; g < 4; ++g)
#pragma unroll
            for (int n = 0; n < 2; ++n)
                acc[g][n] = (f32x4){bias_r[g][n], bias_r[g][n], bias_r[g][n], bias_r[g][n]};

        const bf16_t* arow = &hxx[cur][col * 328 + kb * 8];
        {
            bf16x8 a8 = *(const bf16x8*)(arow + 8 * 32);
            bf16x8 a9 = *(const bf16x8*)(arow + 9 * 32);
#pragma unroll
            for (int g = 0; g < 4; ++g)
#pragma unroll
                for (int n = 0; n < 2; ++n) {
                    acc[g][n] = __builtin_amdgcn_mfma_f32_16x16x32_bf16(a8, bW[g][n][8], acc[g][n], 0, 0, 0);
                    acc[g][n] = __builtin_amdgcn_mfma_f32_16x16x32_bf16(a9, bW[g][n][9], acc[g][n], 0, 0, 0);
                }
        }
        if (t > 0) {
#pragma unroll
            for (int ks = 0; ks < 8; ++ks) {
                bf16x8 a = *(const bf16x8*)(arow + ks * 32);
#pragma unroll
                for (int g = 0; g < 4; ++g)
#pragma unroll
                    for (int n = 0; n < 2; ++n)
                        acc[g][n] = __builtin_amdgcn_mfma_f32_16x16x32_bf16(a, bW[g][n][ks], acc[g][n], 0, 0, 0);
            }
        }

        // ---- P3: in-register epilogue; h -> hxx[nxt] own cols + pub ----
        bf16_t* pub = exch + ((size_t)bid * 2 + cur) * 2048;
        float hv[2][4];
#pragma unroll
        for (int n = 0; n < 2; ++n)
#pragma unroll
            for (int r = 0; r < 4; ++r) {
                float gi = sigmoid_f(acc[0][n][r]);
                float gf = sigmoid_f(acc[1][n][r]);
                float gg = tanh_f(acc[2][n][r]);
                float go = sigmoid_f(acc[3][n][r]);
                float c  = gf * c_st[n][r] + gi * gg;
                c_st[n][r] = c;
                float h  = go * tanh_f(c);
                hv[n][r] = h;
                bf16_t hb = (bf16_t)h;
                const int row = kb * 4 + r;
                const int jl  = jbase + n * 16 + col;      // 0..127 within half
                hxx[nxt][row * 328 + half * 128 + jl] = hb; // own A for next step
                pub[row * 128 + jl]                   = hb; // partner's A
            }
        __syncthreads();                                   // B0: pub stores drained
        if (tid == 0)
            __hip_atomic_store(flag_me, t + 1, __ATOMIC_RELAXED, __HIP_MEMORY_SCOPE_AGENT);

        // out stores AFTER release (drain overlaps next step's spin)
#pragma unroll
        for (int n = 0; n < 2; ++n)
#pragma unroll
            for (int r = 0; r < 4; ++r) {
                const int row = kb * 4 + r;
                const int bg  = group * 16 + row;
                const int jg  = half * 128 + jbase + n * 16 + col;
                out[((size_t)bg * TSTEPS + t) * HID + jg] = hv[n][r];
            }
        if (t == TSTEPS - 1) {
            float* hn = out + (size_t)BATCH * TSTEPS * HID;
            float* cn = hn + (size_t)BATCH * HID;
#pragma unroll
            for (int n = 0; n < 2; ++n)
#pragma unroll
                for (int r = 0; r < 4; ++r) {
                    const int row = kb * 4 + r;
                    const int bg  = group * 16 + row;
                    const int jg  = half * 128 + jbase + n * 16 + col;
                    hn[(size_t)bg * HID + jg] = hv[n][r];
                    cn[(size_t)bg * HID + jg] = c_st[n][r];
                }
        }
    }
}

extern "C" void kernel_launch(void* const* d_in, const int* in_sizes, int n_in,
                              void* d_out, int out_size, void* d_ws, size_t ws_size,
                              hipStream_t stream)
{
    (void)in_sizes; (void)n_in; (void)out_size; (void)ws_size;
    const float* x   = (const float*)d_in[0];
    const float* Wii = (const float*)d_in[1];
    const float* bii = (const float*)d_in[2];
    const float* Wif = (const float*)d_in[3];
    const float* bif = (const float*)d_in[4];
    const float* Wig = (const float*)d_in[5];
    const float* big = (const float*)d_in[6];
    const float* Wio = (const float*)d_in[7];
    const float* bio = (const float*)d_in[8];
    const float* Whi = (const float*)d_in[9];
    const float* bhi = (const float*)d_in[10];
    const float* Whf = (const float*)d_in[11];
    const float* bhf = (const float*)d_in[12];
    const float* Whg = (const float*)d_in[13];
    const float* bhg = (const float*)d_in[14];
    const float* Who = (const float*)d_in[15];
    const float* bho = (const float*)d_in[16];

    char* ws = (char*)d_ws;
    bf16_t* wpack = (bf16_t*)(ws + WPACK_OFF);
    float*  bias  = (float*)(ws + BIAS_OFF);
    bf16_t* exch  = (bf16_t*)(ws + EXCH_OFF);
    int*    flags = (int*)(ws + FLAG_OFF);

    lstm_prep<<<(1024 * KTOT + 255) / 256, 256, 0, stream>>>(
        Wii, Wif, Wig, Wio, Whi, Whf, Whg, Who,
        bii, bif, big, bio, bhi, bhf, bhg, bho,
        wpack, bias, flags);

    lstm_main<<<16, 256, 0, stream>>>(
        x, wpack, bias, (float*)d_out, exch, flags);
}

// Round 11
// 2583.656 us; speedup vs baseline: 1.1658x; 1.1658x over previous
//
#include <hip/hip_runtime.h>

#define INPUT 64
#define HID 256
#define BATCH 128
#define TSTEPS 1000
#define KTOT 320            // 256 (h) + 64 (x)

typedef __bf16 bf16_t;
typedef __bf16 bf16x8 __attribute__((ext_vector_type(8)));
typedef float  f32x4  __attribute__((ext_vector_type(4)));

// ---- ws layout (bytes) ----
#define WPACK_OFF   0
#define WPACK_BYTES (1024 * KTOT * 2)            // 655360
#define BIAS_OFF    (WPACK_OFF + WPACK_BYTES)
#define BIAS_BYTES  (1024 * 4)
#define EXCH_OFF    (BIAS_OFF + BIAS_BYTES)      // 16 blocks x 2 parity x 2048 bf16
#define EXCH_BYTES  (16 * 2 * 2048 * 2)          // 131072
#define FLAG_OFF    (EXCH_OFF + EXCH_BYTES)      // 16 flags, 256B apart

__global__ void lstm_prep(
    const float* __restrict__ Wii, const float* __restrict__ Wif,
    const float* __restrict__ Wig, const float* __restrict__ Wio,
    const float* __restrict__ Whi, const float* __restrict__ Whf,
    const float* __restrict__ Whg, const float* __restrict__ Who,
    const float* __restrict__ bii, const float* __restrict__ bif,
    const float* __restrict__ big, const float* __restrict__ bio,
    const float* __restrict__ bhi, const float* __restrict__ bhf,
    const float* __restrict__ bhg, const float* __restrict__ bho,
    bf16_t* __restrict__ wpack, float* __restrict__ bias,
    int* __restrict__ flags)
{
    int id = blockIdx.x * 256 + threadIdx.x;
    if (id < 1024 * KTOT) {
        int n = id / KTOT, k = id % KTOT;
        int g = n >> 8, j = n & 255;
        const float* Wh = (g == 0) ? Whi : (g == 1) ? Whf : (g == 2) ? Whg : Who;
        const float* Wi = (g == 0) ? Wii : (g == 1) ? Wif : (g == 2) ? Wig : Wio;
        float v = (k < HID) ? Wh[j * HID + k] : Wi[j * INPUT + (k - HID)];
        wpack[id] = (bf16_t)v;
    }
    if (id < 1024) {
        int g = id >> 8, j = id & 255;
        const float* bi = (g == 0) ? bii : (g == 1) ? bif : (g == 2) ? big : bio;
        const float* bh = (g == 0) ? bhi : (g == 1) ? bhf : (g == 2) ? bhg : bho;
        bias[id] = bi[j] + bh[j];
    }
    if (id < 16)
        __hip_atomic_store(flags + id * 64, 0, __ATOMIC_RELAXED, __HIP_MEMORY_SCOPE_AGENT);
}

__device__ __forceinline__ float sigmoid_f(float v) {
    return 1.0f / (1.0f + __expf(-v));
}
__device__ __forceinline__ float tanh_f(float v) {
    return 1.0f - 2.0f / (__expf(2.0f * v) + 1.0f);
}

// 16 blocks x 512 threads. group = bid&7, half = bid>>3 (pair b, b+8).
// Wave w (0..7) owns cols [w*16, w*16+16) of the half, ALL 4 gates:
// 4 x 10 = 40 weight frags = 160 VGPRs. amdgpu_waves_per_eu(2,2): exactly
// 2 waves/SIMD (8 waves/CU), max=2 removes the allocator's occupancy
// incentive to sink the weight loads (the R7 failure mode, VGPR=124).
__global__ __launch_bounds__(512) __attribute__((amdgpu_waves_per_eu(2, 2)))
void lstm_main(
    const float* __restrict__ x, const bf16_t* __restrict__ wpack,
    const float* __restrict__ bias_g, float* __restrict__ out,
    bf16_t* __restrict__ exch, int* __restrict__ flags)
{
    // [parity][16 rows][328 bf16]: K 0..255 = h (both halves), 256..319 = x.
    __shared__ __align__(16) bf16_t hxx[2][16 * 328];

    const int bid   = blockIdx.x;
    const int group = bid & 7;
    const int half  = bid >> 3;
    const int tid   = threadIdx.x;
    const int w     = tid >> 6;          // wave 0..7
    const int l     = tid & 63;
    const int col   = l & 15;
    const int kb    = l >> 4;            // 0..3

    const int jloc  = w * 16 + col;            // 0..127 within half
    const int jglob = half * 128 + jloc;       // 0..255

    // ---- persistent weights: 4 gates x 10 kslices = 40 frags = 160 VGPRs ----
    bf16x8 bW[4][10];
#pragma unroll
    for (int g = 0; g < 4; ++g) {
        const bf16_t* wrow = wpack + (size_t)(g * 256 + jglob) * KTOT;
#pragma unroll
        for (int ks = 0; ks < 10; ++ks)
            bW[g][ks] = *(const bf16x8*)(wrow + ks * 32 + kb * 8);
    }
#pragma unroll
    for (int g = 0; g < 4; ++g)
#pragma unroll
        for (int ks = 0; ks < 10; ++ks)
            asm volatile("" : "+v"(bW[g][ks]));

    float bias_r[4];
#pragma unroll
    for (int g = 0; g < 4; ++g)
        bias_r[g] = bias_g[g * 256 + jglob];

    float c_st[4] = {0.f, 0.f, 0.f, 0.f};

    const int pbid = (1 - half) * 8 + group;
    int*       flag_me = flags + bid * 64;
    const int* flag_pn = flags + pbid * 64;
    const int  pbase   = (1 - half) * 128;     // partner cols in hxx (elements)

    // x staging: thread -> (row xb = tid>>5, 2 f32 at xi)
    const int xb = tid >> 5;
    const int xi = (tid & 31) * 2;
    const float* xbase = x + (size_t)(group * 16 + xb) * (TSTEPS * INPUT) + xi;

    // partner fetch: thread -> (row prow, 4 bf16 at pe0)
    const int prow = tid >> 5;
    const int pe0  = (tid & 31) * 4;

    // prologue: x_0 -> hxx[0], x_1 -> regs
    {
        float2 v = *(const float2*)(xbase);
        hxx[0][xb * 328 + 256 + xi]     = (bf16_t)v.x;
        hxx[0][xb * 328 + 256 + xi + 1] = (bf16_t)v.y;
    }
    float2 xv = *(const float2*)(xbase + INPUT);
    __syncthreads();

#pragma unroll 1
    for (int t = 0; t < TSTEPS; ++t) {
        const int cur = t & 1;
        const int nxt = cur ^ 1;

        // ---- P1: stage x_{t+1} -> hxx[nxt]; fetch partner h_{t-1} -> hxx[cur]
        if (t + 1 < TSTEPS) {
            hxx[nxt][xb * 328 + 256 + xi]     = (bf16_t)xv.x;
            hxx[nxt][xb * 328 + 256 + xi + 1] = (bf16_t)xv.y;
        }
        if (t + 2 < TSTEPS)
            xv = *(const float2*)(xbase + (size_t)(t + 2) * INPUT);
        if (t > 0) {
            if (l == 0) {
                while (__hip_atomic_load(flag_pn, __ATOMIC_RELAXED, __HIP_MEMORY_SCOPE_AGENT) < t) {}
            }
            const bf16_t* src = exch + ((size_t)pbid * 2 + ((t - 1) & 1)) * 2048
                              + prow * 128 + pe0;
            float2 v;
            asm volatile(
                "global_load_dwordx2 %0, %1, off sc0\n\t"
                "s_waitcnt vmcnt(0)"
                : "=&v"(v) : "v"(src) : "memory");
            *(float2*)&hxx[cur][prow * 328 + pbase + pe0] = v;
        }
        __syncthreads();                                   // B1: hxx[cur] complete

        // ---- P2: 40 MFMAs, weights resident ----
        f32x4 acc[4];
#pragma unroll
        for (int g = 0; g < 4; ++g)
            acc[g] = (f32x4){bias_r[g], bias_r[g], bias_r[g], bias_r[g]};

        const bf16_t* arow = &hxx[cur][col * 328 + kb * 8];
        {
            bf16x8 a8 = *(const bf16x8*)(arow + 8 * 32);
            bf16x8 a9 = *(const bf16x8*)(arow + 9 * 32);
#pragma unroll
            for (int g = 0; g < 4; ++g) {
                acc[g] = __builtin_amdgcn_mfma_f32_16x16x32_bf16(a8, bW[g][8], acc[g], 0, 0, 0);
                acc[g] = __builtin_amdgcn_mfma_f32_16x16x32_bf16(a9, bW[g][9], acc[g], 0, 0, 0);
            }
        }
        if (t > 0) {
#pragma unroll
            for (int ks = 0; ks < 8; ++ks) {
                bf16x8 a = *(const bf16x8*)(arow + ks * 32);
#pragma unroll
                for (int g = 0; g < 4; ++g)
                    acc[g] = __builtin_amdgcn_mfma_f32_16x16x32_bf16(a, bW[g][ks], acc[g], 0, 0, 0);
            }
        }

        // ---- P3: in-register epilogue; h -> hxx[nxt] own cols + pub ----
        bf16_t* pub = exch + ((size_t)bid * 2 + cur) * 2048;
        float hv[4];
#pragma unroll
        for (int r = 0; r < 4; ++r) {
            float gi = sigmoid_f(acc[0][r]);
            float gf = sigmoid_f(acc[1][r]);
            float gg = tanh_f(acc[2][r]);
            float go = sigmoid_f(acc[3][r]);
            float c  = gf * c_st[r] + gi * gg;
            c_st[r]  = c;
            float h  = go * tanh_f(c);
            hv[r]    = h;
            bf16_t hb = (bf16_t)h;
            const int row = kb * 4 + r;
            hxx[nxt][row * 328 + jglob] = hb;              // own A for next step
            pub[row * 128 + jloc]       = hb;              // partner's A for next step
        }
        __syncthreads();                                   // B0: pub stores drained
        if (tid == 0)
            __hip_atomic_store(flag_me, t + 1, __ATOMIC_RELAXED, __HIP_MEMORY_SCOPE_AGENT);

        // out stores AFTER release (drain overlaps next step's spin)
#pragma unroll
        for (int r = 0; r < 4; ++r) {
            const int row = kb * 4 + r;
            const int bg  = group * 16 + row;
            out[((size_t)bg * TSTEPS + t) * HID + jglob] = hv[r];
        }
        if (t == TSTEPS - 1) {
            float* hn = out + (size_t)BATCH * TSTEPS * HID;
            float* cn = hn + (size_t)BATCH * HID;
#pragma unroll
            for (int r = 0; r < 4; ++r) {
                const int row = kb * 4 + r;
                const int bg  = group * 16 + row;
                hn[(size_t)bg * HID + jglob] = hv[r];
                cn[(size_t)bg * HID + jglob] = c_st[r];
            }
        }
    }
}

extern "C" void kernel_launch(void* const* d_in, const int* in_sizes, int n_in,
                              void* d_out, int out_size, void* d_ws, size_t ws_size,
                              hipStream_t stream)
{
    (void)in_sizes; (void)n_in; (void)out_size; (void)ws_size;
    const float* x   = (const float*)d_in[0];
    const float* Wii = (const float*)d_in[1];
    const float* bii = (const float*)d_in[2];
    const float* Wif = (const float*)d_in[3];
    const float* bif = (const float*)d_in[4];
    const float* Wig = (const float*)d_in[5];
    const float* big = (const float*)d_in[6];
    const float* Wio = (const float*)d_in[7];
    const float* bio = (const float*)d_in[8];
    const float* Whi = (const float*)d_in[9];
    const float* bhi = (const float*)d_in[10];
    const float* Whf = (const float*)d_in[11];
    const float* bhf = (const float*)d_in[12];
    const float* Whg = (const float*)d_in[13];
    const float* bhg = (const float*)d_in[14];
    const float* Who = (const float*)d_in[15];
    const float* bho = (const float*)d_in[16];

    char* ws = (char*)d_ws;
    bf16_t* wpack = (bf16_t*)(ws + WPACK_OFF);
    float*  bias  = (float*)(ws + BIAS_OFF);
    bf16_t* exch  = (bf16_t*)(ws + EXCH_OFF);
    int*    flags = (int*)(ws + FLAG_OFF);

    lstm_prep<<<(1024 * KTOT + 255) / 256, 256, 0, stream>>>(
        Wii, Wif, Wig, Wio, Whi, Whf, Whg, Who,
        bii, bif, big, bio, bhi, bhf, bhg, bho,
        wpack, bias, flags);

    lstm_main<<<16, 512, 0, stream>>>(
        x, wpack, bias, (float*)d_out, exch, flags);
}

// Round 12
// 2418.739 us; speedup vs baseline: 1.2453x; 1.0682x over previous
//
#include <hip/hip_runtime.h>

#define INPUT 64
#define HID 256
#define BATCH 128
#define TSTEPS 1000
#define KTOT 320            // 256 (h) + 64 (x)

typedef __bf16 bf16_t;
typedef __bf16 bf16x8 __attribute__((ext_vector_type(8)));
typedef float  f32x4  __attribute__((ext_vector_type(4)));

// ---- ws layout (bytes) ----
#define WPACK_OFF   0
#define WPACK_BYTES (1024 * KTOT * 2)            // 655360
#define BIAS_OFF    (WPACK_OFF + WPACK_BYTES)
#define BIAS_BYTES  (1024 * 4)
#define EXCH_OFF    (BIAS_OFF + BIAS_BYTES)      // 32 blocks x 2 parity x 1024 bf16
#define EXCH_BYTES  (32 * 2 * 1024 * 2)          // 131072
#define FLAG_OFF    (EXCH_OFF + EXCH_BYTES)      // 32 flags, 256B apart

__global__ void lstm_prep(
    const float* __restrict__ Wii, const float* __restrict__ Wif,
    const float* __restrict__ Wig, const float* __restrict__ Wio,
    const float* __restrict__ Whi, const float* __restrict__ Whf,
    const float* __restrict__ Whg, const float* __restrict__ Who,
    const float* __restrict__ bii, const float* __restrict__ bif,
    const float* __restrict__ big, const float* __restrict__ bio,
    const float* __restrict__ bhi, const float* __restrict__ bhf,
    const float* __restrict__ bhg, const float* __restrict__ bho,
    bf16_t* __restrict__ wpack, float* __restrict__ bias,
    int* __restrict__ flags)
{
    int id = blockIdx.x * 256 + threadIdx.x;
    if (id < 1024 * KTOT) {
        int n = id / KTOT, k = id % KTOT;
        int g = n >> 8, j = n & 255;
        const float* Wh = (g == 0) ? Whi : (g == 1) ? Whf : (g == 2) ? Whg : Who;
        const float* Wi = (g == 0) ? Wii : (g == 1) ? Wif : (g == 2) ? Wig : Wio;
        float v = (k < HID) ? Wh[j * HID + k] : Wi[j * INPUT + (k - HID)];
        wpack[id] = (bf16_t)v;
    }
    if (id < 1024) {
        int g = id >> 8, j = id & 255;
        const float* bi = (g == 0) ? bii : (g == 1) ? bif : (g == 2) ? big : bio;
        const float* bh = (g == 0) ? bhi : (g == 1) ? bhf : (g == 2) ? bhg : bho;
        bias[id] = bi[j] + bh[j];
    }
    if (id < 32)
        __hip_atomic_store(flags + id * 64, 0, __ATOMIC_RELAXED, __HIP_MEMORY_SCOPE_AGENT);
}

__device__ __forceinline__ float sigmoid_f(float v) {
    return 1.0f / (1.0f + __expf(-v));
}
__device__ __forceinline__ float tanh_f(float v) {
    return 1.0f - 2.0f / (__expf(2.0f * v) + 1.0f);
}

// 32 blocks x 256 threads. group = bid&7 (16 batch rows), qtr = bid>>3
// (64 cols x all 4 gates). Wave w owns cols [w*16,w*16+16): 40 weight frags
// = 160 VGPRs, resident at 256thr+waves_per_eu(1,1) (the proven allocator
// mode). Exchange is DEVICE-COHERENT (sc0 sc1 through MALL) -> correctness
// does not depend on block->XCD placement (the R6/R8/R10 failure mechanism).
__global__ __launch_bounds__(256) __attribute__((amdgpu_waves_per_eu(1, 1)))
void lstm_main(
    const float* __restrict__ x, const bf16_t* __restrict__ wpack,
    const float* __restrict__ bias_g, float* __restrict__ out,
    bf16_t* __restrict__ exch, int* __restrict__ flags)
{
    // [parity][16 rows][328 bf16]: K 0..255 = h (all quarters), 256..319 = x.
    __shared__ __align__(16) bf16_t hxx[2][16 * 328];

    const int bid   = blockIdx.x;
    const int group = bid & 7;
    const int qtr   = bid >> 3;          // 0..3
    const int tid   = threadIdx.x;
    const int w     = tid >> 6;          // wave 0..3
    const int l     = tid & 63;
    const int col   = l & 15;
    const int kb    = l >> 4;            // 0..3

    const int jblk  = w * 16 + col;            // 0..63 within quarter
    const int jglob = qtr * 64 + jblk;         // 0..255

    // ---- persistent weights: 4 gates x 10 kslices = 40 frags = 160 VGPRs ----
    bf16x8 bW[4][10];
#pragma unroll
    for (int g = 0; g < 4; ++g) {
        const bf16_t* wrow = wpack + (size_t)(g * 256 + jglob) * KTOT;
#pragma unroll
        for (int ks = 0; ks < 10; ++ks)
            bW[g][ks] = *(const bf16x8*)(wrow + ks * 32 + kb * 8);
    }
#pragma unroll
    for (int g = 0; g < 4; ++g)
#pragma unroll
        for (int ks = 0; ks < 10; ++ks)
            asm volatile("" : "+v"(bW[g][ks]));

    float bias_r[4];
#pragma unroll
    for (int g = 0; g < 4; ++g)
        bias_r[g] = bias_g[g * 256 + jglob];

    float c_st[4] = {0.f, 0.f, 0.f, 0.f};

    int* flag_me = flags + bid * 64;
    // partner fetch mapping: threads 0..191, p = tid>>6 (3 partners),
    // i = tid&63: row = i>>2, c16 = (i&3)*16 (32B per thread)
    const int p      = tid >> 6;                     // == w
    const int pi     = tid & 63;
    const int pqtr   = (qtr + 1 + p) & 3;            // valid for p<3
    const int pbid   = pqtr * 8 + group;
    const int* flag_pn = flags + pbid * 64;
    const int prow   = pi >> 2;
    const int pc16   = (pi & 3) * 16;

    // x staging: thread -> (row xr, 4 f32 at xi0)
    const int xr  = tid >> 4;
    const int xi0 = (tid & 15) * 4;
    const float* xbase = x + (size_t)(group * 16 + xr) * (TSTEPS * INPUT) + xi0;

    // prologue: x_0 -> hxx[0], x_1 -> regs
    {
        float4 v = *(const float4*)(xbase);
        bf16_t* d = &hxx[0][xr * 328 + 256 + xi0];
        d[0] = (bf16_t)v.x; d[1] = (bf16_t)v.y; d[2] = (bf16_t)v.z; d[3] = (bf16_t)v.w;
    }
    float4 xv = *(const float4*)(xbase + INPUT);
    __syncthreads();

#pragma unroll 1
    for (int t = 0; t < TSTEPS; ++t) {
        const int cur = t & 1;
        const int nxt = cur ^ 1;

        // ---- P1: stage x_{t+1} -> hxx[nxt]; fetch 3 partner pubs -> hxx[cur]
        if (t + 1 < TSTEPS) {
            bf16_t* d = &hxx[nxt][xr * 328 + 256 + xi0];
            d[0] = (bf16_t)xv.x; d[1] = (bf16_t)xv.y; d[2] = (bf16_t)xv.z; d[3] = (bf16_t)xv.w;
        }
        if (t + 2 < TSTEPS)
            xv = *(const float4*)(xbase + (size_t)(t + 2) * INPUT);
        if (t > 0 && w < 3) {
            // self-spin (R5 pattern): every loading thread polls the flag
            while (__hip_atomic_load(flag_pn, __ATOMIC_RELAXED, __HIP_MEMORY_SCOPE_AGENT) < t) {}
            // device-coherent read: bypass L1 AND L2, served by MALL
            const bf16_t* src = exch + ((size_t)pbid * 2 + ((t - 1) & 1)) * 1024
                              + prow * 64 + pc16;
            f32x4 v0, v1;
            asm volatile(
                "global_load_dwordx4 %0, %2, off sc0 sc1\n\t"
                "global_load_dwordx4 %1, %3, off sc0 sc1\n\t"
                "s_waitcnt vmcnt(0)"
                : "=&v"(v0), "=&v"(v1)
                : "v"(src), "v"(src + 8)
                : "memory");
            bf16_t* dst = &hxx[cur][prow * 328 + pqtr * 64 + pc16];
            *(f32x4*)(dst)     = v0;
            *(f32x4*)(dst + 8) = v1;
        }
        __syncthreads();                                   // B1: hxx[cur] complete

        // ---- P2: 40 MFMAs, weights resident ----
        f32x4 acc[4];
#pragma unroll
        for (int g = 0; g < 4; ++g)
            acc[g] = (f32x4){bias_r[g], bias_r[g], bias_r[g], bias_r[g]};

        const bf16_t* arow = &hxx[cur][col * 328 + kb * 8];
        {
            bf16x8 a8 = *(const bf16x8*)(arow + 8 * 32);
            bf16x8 a9 = *(const bf16x8*)(arow + 9 * 32);
#pragma unroll
            for (int g = 0; g < 4; ++g) {
                acc[g] = __builtin_amdgcn_mfma_f32_16x16x32_bf16(a8, bW[g][8], acc[g], 0, 0, 0);
                acc[g] = __builtin_amdgcn_mfma_f32_16x16x32_bf16(a9, bW[g][9], acc[g], 0, 0, 0);
            }
        }
        if (t > 0) {
#pragma unroll
            for (int ks = 0; ks < 8; ++ks) {
                bf16x8 a = *(const bf16x8*)(arow + ks * 32);
#pragma unroll
                for (int g = 0; g < 4; ++g)
                    acc[g] = __builtin_amdgcn_mfma_f32_16x16x32_bf16(a, bW[g][ks], acc[g], 0, 0, 0);
            }
        }

        // ---- P3: in-register epilogue; h -> hxx[nxt] own cols + pub (sc1) ----
        bf16_t* pub = exch + ((size_t)bid * 2 + cur) * 1024;
        float hv[4];
#pragma unroll
        for (int r = 0; r < 4; ++r) {
            float gi = sigmoid_f(acc[0][r]);
            float gf = sigmoid_f(acc[1][r]);
            float gg = tanh_f(acc[2][r]);
            float go = sigmoid_f(acc[3][r]);
            float c  = gf * c_st[r] + gi * gg;
            c_st[r]  = c;
            float h  = go * tanh_f(c);
            hv[r]    = h;
            bf16_t hb = (bf16_t)h;
            const int row = kb * 4 + r;
            hxx[nxt][row * 328 + jglob] = hb;              // own A for next step
            // device-coherent pub store (write-through to MALL)
            unsigned int hbits = (unsigned int)__builtin_bit_cast(unsigned short, hb);
            const bf16_t* paddr = pub + row * 64 + jblk;
            asm volatile("global_store_short %0, %1, off sc0 sc1"
                         :: "v"(paddr), "v"(hbits) : "memory");
        }
        // drain the asm stores (compiler doesn't track inline-asm VMEM)
        asm volatile("s_waitcnt vmcnt(0)" ::: "memory");
        __syncthreads();                                   // B0: all pubs at MALL
        if (tid == 0)
            __hip_atomic_store(flag_me, t + 1, __ATOMIC_RELAXED, __HIP_MEMORY_SCOPE_AGENT);

        // out stores AFTER release (drain overlaps next step's spin)
#pragma unroll
        for (int r = 0; r < 4; ++r) {
            const int row = kb * 4 + r;
            const int bg  = group * 16 + row;
            out[((size_t)bg * TSTEPS + t) * HID + jglob] = hv[r];
        }
        if (t == TSTEPS - 1) {
            float* hn = out + (size_t)BATCH * TSTEPS * HID;
            float* cn = hn + (size_t)BATCH * HID;
#pragma unroll
            for (int r = 0; r < 4; ++r) {
                const int row = kb * 4 + r;
                const int bg  = group * 16 + row;
                hn[(size_t)bg * HID + jglob] = hv[r];
                cn[(size_t)bg * HID + jglob] = c_st[r];
            }
        }
    }
}

extern "C" void kernel_launch(void* const* d_in, const int* in_sizes, int n_in,
                              void* d_out, int out_size, void* d_ws, size_t ws_size,
                              hipStream_t stream)
{
    (void)in_sizes; (void)n_in; (void)out_size; (void)ws_size;
    const float* x   = (const float*)d_in[0];
    const float* Wii = (const float*)d_in[1];
    const float* bii = (const float*)d_in[2];
    const float* Wif = (const float*)d_in[3];
    const float* bif = (const float*)d_in[4];
    const float* Wig = (const float*)d_in[5];
    const float* big = (const float*)d_in[6];
    const float* Wio = (const float*)d_in[7];
    const float* bio = (const float*)d_in[8];
    const float* Whi = (const float*)d_in[9];
    const float* bhi = (const float*)d_in[10];
    const float* Whf = (const float*)d_in[11];
    const float* bhf = (const float*)d_in[12];
    const float* Whg = (const float*)d_in[13];
    const float* bhg = (const float*)d_in[14];
    const float* Who = (const float*)d_in[15];
    const float* bho = (const float*)d_in[16];

    char* ws = (char*)d_ws;
    bf16_t* wpack = (bf16_t*)(ws + WPACK_OFF);
    float*  bias  = (float*)(ws + BIAS_OFF);
    bf16_t* exch  = (bf16_t*)(ws + EXCH_OFF);
    int*    flags = (int*)(ws + FLAG_OFF);

    lstm_prep<<<(1024 * KTOT + 255) / 256, 256, 0, stream>>>(
        Wii, Wif, Wig, Wio, Whi, Whf, Whg, Who,
        bii, bif, big, bio, bhi, bhf, bhg, bho,
        wpack, bias, flags);

    lstm_main<<<32, 256, 0, stream>>>(
        x, wpack, bias, (float*)d_out, exch, flags);
}